// Round 4
// baseline (591.225 us; speedup 1.0000x reference)
//
#include <hip/hip_runtime.h>
#include <hip/hip_bf16.h>
#include <float.h>

#define N_SRC 1024
#define N_TGT 100000
#define DIM   1024
#define KNN   4

// GEMM geometry: M = targets, N = sources.
#define TB 128
#define SB 128
#define KB 32
#define NK (DIM / KB)                // 32
#define NMB ((N_TGT + TB - 1) / TB)  // 782 target panels
#define NSC (N_SRC / SB)             // 8 source chunks
#define NSTRIP (NMB * 2)             // 1564
#define NCAND (NSTRIP * KNN)         // 6256 candidates per source row
#define RERANK 16

typedef __attribute__((ext_vector_type(8))) short bf16x8;
typedef __attribute__((ext_vector_type(4))) float f32x4;
typedef __attribute__((ext_vector_type(4))) unsigned int u32x4;

// bf16 truncation pack: one v_perm_b32 for two floats.
__device__ __forceinline__ unsigned int pack_trunc(float a, float b) {
    return __builtin_amdgcn_perm(__builtin_bit_cast(unsigned int, b),
                                 __builtin_bit_cast(unsigned int, a),
                                 0x07060302u);
}

__device__ __forceinline__ void gload16(const void* gp, void* lp) {
    __builtin_amdgcn_global_load_lds(
        (const __attribute__((address_space(1))) void*)gp,
        (__attribute__((address_space(3))) void*)lp, 16, 0, 0);
}

// ---------------------------------------------------------------------------
// Kernel 1: convert sources f32 -> bf16 into ws, tiled [ks][1024 rows][64 B],
// LDS slot swizzle pre-applied (slot holds content slot ^ ((row>>1)&3)).
// ---------------------------------------------------------------------------
__global__ __launch_bounds__(256) void convert_src_kernel(
    const float* __restrict__ src, unsigned int* __restrict__ srcws)
{
    int gid  = blockIdx.x * 256 + threadIdx.x;   // one 16B chunk; 131072 total
    int ks   = gid >> 12;
    int rem  = gid & 4095;
    int row  = rem >> 2;
    int slot = rem & 3;
    int kin  = ks * KB + ((slot ^ ((row >> 1) & 3)) << 3);
    const float4* p = (const float4*)(src + (size_t)row * DIM + kin);
    float4 a = p[0], b = p[1];
    u32x4 o = { pack_trunc(a.x, a.y), pack_trunc(a.z, a.w),
                pack_trunc(b.x, b.y), pack_trunc(b.z, b.w) };
    ((u32x4*)srcws)[gid] = o;
}

// ---------------------------------------------------------------------------
// Kernel 2: bf16 MFMA GEMM + per-wave per-source-column top-4 + in-block
// target norms. 3-buffer LDS rotation, 2-deep A-reg pipeline, counted
// vmcnt(6) + raw s_barrier: prefetch stays in flight ACROSS barriers (T3/T4).
// ---------------------------------------------------------------------------
__global__ __launch_bounds__(256, 3) void gemm_topk_kernel(
    const float* __restrict__ tgt, const void* __restrict__ srcws,
    float* __restrict__ cand_val, int* __restrict__ cand_idx)
{
    __shared__ __align__(16) unsigned short As[3][TB][KB];  // 24 KB
    __shared__ __align__(16) unsigned short Bs[3][SB][KB];  // 24 KB
    __shared__ float nsq_sh[256];
    __shared__ float invn_sh[TB];

    const int b = blockIdx.x;
    const int logical = (b & 7) * ((NMB * NSC) / 8) + (b >> 3);
    const int mblk = logical >> 3;
    const int schk = logical & 7;
    const int m0 = mblk * TB;
    const int c0 = schk * SB;
    const int t = threadIdx.x;
    const int lane = t & 63;
    const int w = t >> 6;
    const int wm = w >> 1, wn = w & 1;
    const int g = lane >> 4, li = lane & 15;

    // A staging role: thread t -> row r, k-half h.
    const int r  = t & 127;
    const int h  = t >> 7;
    const int sr = (r >> 1) & 3;
    const int wslot0 = (2 * h) ^ sr;
    const int wslot1 = (2 * h + 1) ^ sr;
    const bool tvalid = (m0 + r) < N_TGT;
    const float* tgp = tgt + (size_t)(m0 + r) * DIM + h * 16;

    // B gload role: wave w fills LDS rows [w*32, w*32+32) via 2 instrs.
    const size_t bofs = ((size_t)(c0 + w * 32) * 64) + (size_t)lane * 16;
    const char* srcb = (const char*)srcws;

    f32x4 acc[4][4];
    #pragma unroll
    for (int i = 0; i < 4; ++i)
        #pragma unroll
        for (int j = 0; j < 4; ++j) acc[i][j] = (f32x4){0.f, 0.f, 0.f, 0.f};

    float nsq = 0.f;
    float4 pa0, pa1, pa2, pa3;   // even-ks A regs
    float4 pb0, pb1, pb2, pb3;   // odd-ks A regs

    unsigned short *Ac = &As[0][0][0], *An1 = &As[1][0][0], *An2 = &As[2][0][0];
    unsigned short *Bc = &Bs[0][0][0], *Bn1 = &Bs[1][0][0], *Bn2 = &Bs[2][0][0];

    const int sw = (li >> 1) & 3;
    const int ro = (g ^ sw) * 8;

    #define LOAD_A(d0, d1, d2, d3, ks_) do {                                  \
        if (tvalid) {                                                         \
            const float4* p_ = (const float4*)(tgp + (ks_) * KB);             \
            d0 = p_[0]; d1 = p_[1]; d2 = p_[2]; d3 = p_[3];                   \
        } else {                                                              \
            d0 = d1 = d2 = d3 = make_float4(0.f, 0.f, 0.f, 0.f);              \
        }                                                                     \
    } while (0)

    #define STAGE_B(bbase_, ks_) do {                                         \
        const char* gp_ = srcb + (size_t)(ks_) * 65536 + bofs;                \
        gload16(gp_,        (bbase_) + (w * 32) * KB);                        \
        gload16(gp_ + 1024, (bbase_) + (w * 32 + 16) * KB);                   \
    } while (0)

    #define PACK_WRITE_A(abase_, s0, s1, s2, s3) do {                         \
        nsq += s0.x*s0.x + s0.y*s0.y + s0.z*s0.z + s0.w*s0.w                  \
             + s1.x*s1.x + s1.y*s1.y + s1.z*s1.z + s1.w*s1.w                  \
             + s2.x*s2.x + s2.y*s2.y + s2.z*s2.z + s2.w*s2.w                  \
             + s3.x*s3.x + s3.y*s3.y + s3.z*s3.z + s3.w*s3.w;                 \
        u32x4 p0_ = { pack_trunc(s0.x, s0.y), pack_trunc(s0.z, s0.w),         \
                      pack_trunc(s1.x, s1.y), pack_trunc(s1.z, s1.w) };       \
        u32x4 p1_ = { pack_trunc(s2.x, s2.y), pack_trunc(s2.z, s2.w),         \
                      pack_trunc(s3.x, s3.y), pack_trunc(s3.z, s3.w) };       \
        *(u32x4*)((abase_) + r * KB + wslot0 * 8) = p0_;                      \
        *(u32x4*)((abase_) + r * KB + wslot1 * 8) = p1_;                      \
    } while (0)

    #define FRAG_READ(abase_, bbase_) do {                                    \
        _Pragma("unroll")                                                     \
        for (int mf = 0; mf < 4; ++mf)                                        \
            af[mf] = *(const bf16x8*)((abase_) +                              \
                        (wm * 64 + mf * 16 + li) * KB + ro);                  \
        _Pragma("unroll")                                                     \
        for (int nf = 0; nf < 4; ++nf)                                        \
            bfr[nf] = *(const bf16x8*)((bbase_) +                             \
                        (wn * 64 + nf * 16 + li) * KB + ro);                  \
    } while (0)

    #define MFMA_DO do {                                                      \
        _Pragma("unroll")                                                     \
        for (int mf = 0; mf < 4; ++mf)                                        \
            _Pragma("unroll")                                                 \
            for (int nf = 0; nf < 4; ++nf)                                    \
                acc[mf][nf] = __builtin_amdgcn_mfma_f32_16x16x32_bf16(        \
                    af[mf], bfr[nf], acc[mf][nf], 0, 0, 0);                   \
    } while (0)

    // counted-vmcnt barrier: prefetch (6 newest vmem ops) stays in flight
    #define PIPE_BARRIER6 do {                                                \
        asm volatile("s_waitcnt vmcnt(6) lgkmcnt(0)" ::: "memory");           \
        __builtin_amdgcn_sched_barrier(0);                                    \
        __builtin_amdgcn_s_barrier();                                         \
    } while (0)

    #define PIPE_BARRIER0 do {                                                \
        asm volatile("s_waitcnt vmcnt(0) lgkmcnt(0)" ::: "memory");           \
        __builtin_amdgcn_sched_barrier(0);                                    \
        __builtin_amdgcn_s_barrier();                                         \
    } while (0)

    #define ROTATE do {                                                       \
        unsigned short* tmp_;                                                 \
        tmp_ = Ac; Ac = An1; An1 = An2; An2 = tmp_;                           \
        tmp_ = Bc; Bc = Bn1; Bn1 = Bn2; Bn2 = tmp_;                           \
    } while (0)

    // ---- prologue: A(0)->pa, B(0)->Bc, A(1)->pb, B(1)->Bn1
    LOAD_A(pa0, pa1, pa2, pa3, 0);
    STAGE_B(Bc, 0);
    LOAD_A(pb0, pb1, pb2, pb3, 1);
    STAGE_B(Bn1, 1);
    PACK_WRITE_A(Ac, pa0, pa1, pa2, pa3);   // compiler waits A(0) only
    PIPE_BARRIER6;                          // drains B(0); A(1),B(1) in flight

    // ---- main loop: 15 pairs (ks = 0..29), then peel ks=30,31
    for (int kp = 0; kp < 15; ++kp) {
        const int ks = 2 * kp;
        bf16x8 af[4], bfr[4];
        // even body (ks): pack pb=A(ks+1), load pa=A(ks+2)
        FRAG_READ(Ac, Bc);
        LOAD_A(pa0, pa1, pa2, pa3, ks + 2);
        STAGE_B(Bn2, ks + 2);
        MFMA_DO;
        PACK_WRITE_A(An1, pb0, pb1, pb2, pb3);
        PIPE_BARRIER6;
        ROTATE;
        // odd body (ks+1): pack pa=A(ks+2), load pb=A(ks+3)
        FRAG_READ(Ac, Bc);
        LOAD_A(pb0, pb1, pb2, pb3, ks + 3);
        STAGE_B(Bn2, ks + 3);
        MFMA_DO;
        PACK_WRITE_A(An1, pa0, pa1, pa2, pa3);
        PIPE_BARRIER6;
        ROTATE;
    }
    {   // ks = 30: no new issues; pack A(31)=pb
        bf16x8 af[4], bfr[4];
        FRAG_READ(Ac, Bc);
        MFMA_DO;
        PACK_WRITE_A(An1, pb0, pb1, pb2, pb3);
        PIPE_BARRIER0;
        ROTATE;
    }
    {   // ks = 31: compute only
        bf16x8 af[4], bfr[4];
        FRAG_READ(Ac, Bc);
        MFMA_DO;
    }

    // ---- in-block target inverse norms (exact f32)
    nsq_sh[t] = nsq;
    __syncthreads();
    if (t < TB) {
        float s = nsq_sh[t] + nsq_sh[t + 128];
        invn_sh[t] = ((m0 + t) < N_TGT) ? 1.0f / sqrtf(s) : -1.0f;
    }
    __syncthreads();

    // ---- epilogue: scale, per-source-column top-4 over this wave's 64 rows
    float invr[4][4];
    #pragma unroll
    for (int mf = 0; mf < 4; ++mf)
        #pragma unroll
        for (int j = 0; j < 4; ++j)
            invr[mf][j] = invn_sh[wm * 64 + mf * 16 + g * 4 + j];

    const int strip = mblk * 2 + wm;
    #pragma unroll
    for (int nf = 0; nf < 4; ++nf) {
        const int scol = c0 + wn * 64 + nf * 16 + li;
        float s[4][4];
        #pragma unroll
        for (int mf = 0; mf < 4; ++mf)
            #pragma unroll
            for (int j = 0; j < 4; ++j)
                s[mf][j] = (invr[mf][j] > 0.f) ? acc[mf][nf][j] * invr[mf][j]
                                               : -FLT_MAX;
        #pragma unroll
        for (int it = 0; it < KNN; ++it) {
            float bv = -FLT_MAX; int bli = 0;
            #pragma unroll
            for (int mf = 0; mf < 4; ++mf)
                #pragma unroll
                for (int j = 0; j < 4; ++j) {
                    int id = mf * 16 + g * 4 + j;
                    if (s[mf][j] > bv) { bv = s[mf][j]; bli = id; }
                }
            #pragma unroll
            for (int off = 16; off < 64; off <<= 1) {
                float ov = __shfl_xor(bv, off);
                int   oi = __shfl_xor(bli, off);
                if (ov > bv || (ov == bv && oi < bli)) { bv = ov; bli = oi; }
            }
            const int mfw = bli >> 4, gw = (bli >> 2) & 3, jw = bli & 3;
            if (g == gw) {
                #pragma unroll
                for (int mf = 0; mf < 4; ++mf)
                    #pragma unroll
                    for (int j = 0; j < 4; ++j)
                        if (mf == mfw && j == jw) s[mf][j] = -FLT_MAX;
            }
            if (g == it) {
                size_t o = ((size_t)scol * NSTRIP + strip) * KNN + it;
                cand_val[o] = bv;
                cand_idx[o] = m0 + wm * 64 + bli;
            }
        }
    }
}

// ---------------------------------------------------------------------------
// Kernel 3: per source row — candidate top-16, exact f32 rerank, top-4,
// gather + mean.
// ---------------------------------------------------------------------------
__global__ __launch_bounds__(256) void merge_rerank_kernel(
    const float* __restrict__ src, const float* __restrict__ tgt,
    const float* __restrict__ cand_val, const int* __restrict__ cand_idx,
    float* __restrict__ out)
{
    __shared__ float sv[NCAND];          // 25 KB
    __shared__ float red_v[4];
    __shared__ int   red_p[4];
    __shared__ int   topi[RERANK];
    __shared__ float rsim[RERANK];
    __shared__ int   ridx[RERANK];
    __shared__ int   sel[KNN];

    const int row = blockIdx.x;
    const int t = threadIdx.x, lane = t & 63, w = t >> 6;
    const float* cv = cand_val + (size_t)row * NCAND;
    const int*   ci = cand_idx + (size_t)row * NCAND;

    for (int i = t; i < NCAND; i += 256) sv[i] = cv[i];
    __syncthreads();

    for (int it = 0; it < RERANK; ++it) {
        float bv = -FLT_MAX; int bp = 0;
        for (int i = t; i < NCAND; i += 256) {
            float v = sv[i];
            if (v > bv) { bv = v; bp = i; }
        }
        #pragma unroll
        for (int off = 1; off < 64; off <<= 1) {
            float ov = __shfl_xor(bv, off);
            int   op = __shfl_xor(bp, off);
            if (ov > bv || (ov == bv && op < bp)) { bv = ov; bp = op; }
        }
        if (lane == 0) { red_v[w] = bv; red_p[w] = bp; }
        __syncthreads();
        if (t == 0) {
            float Bv = red_v[0]; int Bp = red_p[0];
            for (int q = 1; q < 4; ++q)
                if (red_v[q] > Bv || (red_v[q] == Bv && red_p[q] < Bp)) {
                    Bv = red_v[q]; Bp = red_p[q];
                }
            topi[it] = ci[Bp];
            sv[Bp] = -FLT_MAX;
        }
        __syncthreads();
    }

    // exact f32 rerank: dot AND target norm from the same row read
    const float4* sp = (const float4*)(src + (size_t)row * DIM);
    #pragma unroll
    for (int q = 0; q < 4; ++q) {
        int cidx = topi[w + 4 * q];
        const float4* tp = (const float4*)(tgt + (size_t)cidx * DIM);
        float a = 0.f, nn = 0.f;
        #pragma unroll
        for (int p = 0; p < 4; ++p) {
            float4 x = sp[lane + 64 * p], y = tp[lane + 64 * p];
            a  = fmaf(x.x, y.x, a);  a  = fmaf(x.y, y.y, a);
            a  = fmaf(x.z, y.z, a);  a  = fmaf(x.w, y.w, a);
            nn = fmaf(y.x, y.x, nn); nn = fmaf(y.y, y.y, nn);
            nn = fmaf(y.z, y.z, nn); nn = fmaf(y.w, y.w, nn);
        }
        #pragma unroll
        for (int off = 1; off < 64; off <<= 1) {
            a  += __shfl_xor(a, off);
            nn += __shfl_xor(nn, off);
        }
        if (lane == 0) { rsim[w + 4 * q] = a / sqrtf(nn); ridx[w + 4 * q] = cidx; }
    }
    __syncthreads();

    if (w == 0) {
        float v = (lane < RERANK) ? rsim[lane] : -FLT_MAX;
        int  ix = (lane < RERANK) ? ridx[lane] : 0x7fffffff;
        #pragma unroll
        for (int it = 0; it < KNN; ++it) {
            float bv = v; int bix = ix;
            #pragma unroll
            for (int off = 1; off < 16; off <<= 1) {
                float ov = __shfl_xor(bv, off);
                int   oi = __shfl_xor(bix, off);
                if (ov > bv || (ov == bv && oi < bix)) { bv = ov; bix = oi; }
            }
            if (lane == 0) sel[it] = bix;
            if (ix == bix) v = -FLT_MAX;
        }
    }
    __syncthreads();

    const float4* g0 = (const float4*)(tgt + (size_t)sel[0] * DIM);
    const float4* g1 = (const float4*)(tgt + (size_t)sel[1] * DIM);
    const float4* g2 = (const float4*)(tgt + (size_t)sel[2] * DIM);
    const float4* g3 = (const float4*)(tgt + (size_t)sel[3] * DIM);
    float4* po = (float4*)(out + (size_t)row * DIM);
    float4 v0 = g0[t], v1 = g1[t], v2 = g2[t], v3 = g3[t];
    float4 rr;
    rr.x = (v0.x + v1.x + v2.x + v3.x) * 0.25f;
    rr.y = (v0.y + v1.y + v2.y + v3.y) * 0.25f;
    rr.z = (v0.z + v1.z + v2.z + v3.z) * 0.25f;
    rr.w = (v0.w + v1.w + v2.w + v3.w) * 0.25f;
    po[t] = rr;
}

// ---------------------------------------------------------------------------
extern "C" void kernel_launch(void* const* d_in, const int* in_sizes, int n_in,
                              void* d_out, int out_size, void* d_ws, size_t ws_size,
                              hipStream_t stream)
{
    const float* src = (const float*)d_in[0];
    const float* tgt = (const float*)d_in[1];
    float* out = (float*)d_out;

    unsigned int* srcws = (unsigned int*)d_ws;
    float* cand_val = (float*)((char*)d_ws + (2u << 20));
    int*   cand_idx = (int*)(cand_val + (size_t)N_SRC * NCAND);

    convert_src_kernel<<<512, 256, 0, stream>>>(src, srcws);

    gemm_topk_kernel<<<NMB * NSC, 256, 0, stream>>>(tgt, srcws,
                                                    cand_val, cand_idx);

    merge_rerank_kernel<<<N_SRC, 256, 0, stream>>>(src, tgt,
                                                   cand_val, cand_idx, out);
}

// Round 5
// 533.713 us; speedup vs baseline: 1.1078x; 1.1078x over previous
//
#include <hip/hip_runtime.h>
#include <hip/hip_bf16.h>
#include <float.h>

#define N_SRC 1024
#define N_TGT 100000
#define DIM   1024
#define KNN   4

// GEMM geometry: M = targets (256/block), N = sources (256/block), BK=64.
#define TB 256
#define SBn 256
#define BK 64
#define NKT (DIM / BK)               // 16 K-tiles
#define NMB (100096 / TB)            // 391 target panels (exact: 391*256=100096)
#define NSC (N_SRC / SBn)            // 4 source chunks
#define NBLK (NMB * NSC)             // 1564
#define NSTRIP (NMB * 2)             // 782 strips of 128 rows
#define NCAND (NSTRIP * KNN)         // 3128 candidates per source row
#define RERANK 16

typedef __attribute__((ext_vector_type(8))) short bf16x8;
typedef __attribute__((ext_vector_type(4))) float f32x4;
typedef __attribute__((ext_vector_type(4))) unsigned int u32x4;

// bf16 truncation pack: one v_perm_b32 for two floats (a = lower k index).
__device__ __forceinline__ unsigned int pack_trunc(float a, float b) {
    return __builtin_amdgcn_perm(__builtin_bit_cast(unsigned int, b),
                                 __builtin_bit_cast(unsigned int, a),
                                 0x07060302u);
}

__device__ __forceinline__ void gload16(const void* gp, void* lp) {
    __builtin_amdgcn_global_load_lds(
        (const __attribute__((address_space(1))) void*)gp,
        (__attribute__((address_space(3))) void*)lp, 16, 0, 0);
}

// ---------------------------------------------------------------------------
// Kernel 1: sources f32 -> bf16 ws, layout [kt][1024 rows][8 slots x 16B],
// slot swizzle pre-applied: position (row, s) holds k-chunk (s ^ (row&7)),
// chunk c = k-window [kt*64 + c*8, +8). GEMM gload_lds's rows linearly.
// ---------------------------------------------------------------------------
__global__ __launch_bounds__(256) void convert_src_kernel(
    const float* __restrict__ src, unsigned int* __restrict__ srcws)
{
    int gid = blockIdx.x * 256 + threadIdx.x;   // 16B chunk id; 131072 total
    int kt  = gid >> 13;
    int rem = gid & 8191;
    int row = rem >> 3;
    int s   = rem & 7;
    int c   = s ^ (row & 7);
    const float4* p = (const float4*)(src + (size_t)row * DIM + kt * 64 + c * 8);
    float4 a = p[0], b = p[1];
    u32x4 o = { pack_trunc(a.x, a.y), pack_trunc(a.z, a.w),
                pack_trunc(b.x, b.y), pack_trunc(b.z, b.w) };
    ((u32x4*)srcws)[gid] = o;
}

// ---------------------------------------------------------------------------
// Kernel 2: 256x256 bf16 MFMA GEMM, 8 waves, 4 phases/K-tile, per-phase
// {ds_read frags | stage} -> bar -> lgkm0 -> setprio/16 MFMA -> bar.
// One vmcnt(0) per K-tile (loads issued 2-3 phases earlier). Per-wave output
// 128 tgt x 64 src; epilogue: per-column top-4 over the wave's 128 rows.
// ---------------------------------------------------------------------------
__global__ __launch_bounds__(512, 2) void gemm_topk_kernel(
    const float* __restrict__ tgt, const void* __restrict__ srcws,
    float* __restrict__ cand_val, int* __restrict__ cand_idx)
{
    __shared__ __align__(16) unsigned short As[2][TB][BK];   // 64 KB
    __shared__ __align__(16) unsigned short Bs[2][SBn][BK];  // 64 KB
    __shared__ float nsq_sh[512];
    __shared__ float invn_sh[TB];

    // bijective XCD swizzle (1564 = 4*196 + 4*195); consecutive logicals on
    // one XCD share a target panel (4 source chunks) -> panel HBM-read once.
    const int b   = blockIdx.x;
    const int xcd = b & 7, sub = b >> 3;
    const int base = (xcd < 4) ? xcd * 196 : 4 * 196 + (xcd - 4) * 195;
    const int logical = base + sub;
    const int mblk = logical >> 2;          // 0..390
    const int schk = logical & 3;           // 0..3
    const int m0 = mblk * TB;
    const int c0 = schk * SBn;

    const int t = threadIdx.x;
    const int lane = t & 63;
    const int w = t >> 6;                   // 8 waves
    const int wm = w >> 2, wn = w & 3;      // 2M x 4N, per-wave 128x64
    const int g = lane >> 4, li = lane & 15;
    const int li7 = li & 7;

    // A staging role: thread t -> row ra (0..255), k-half h (32 floats).
    const int ra = t >> 1;
    const int h  = t & 1;
    const int s0w = (4 * h + 0) ^ (ra & 7);
    const int s1w = (4 * h + 1) ^ (ra & 7);
    const int s2w = (4 * h + 2) ^ (ra & 7);
    const int s3w = (4 * h + 3) ^ (ra & 7);
    const bool tvalid = (m0 + ra) < N_TGT;
    const float* tgp = tgt + (size_t)(m0 + ra) * DIM + h * 32;

    const char* srcb = (const char*)srcws;

    f32x4 acc[8][4];
    #pragma unroll
    for (int i = 0; i < 8; ++i)
        #pragma unroll
        for (int j = 0; j < 4; ++j) acc[i][j] = (f32x4){0.f, 0.f, 0.f, 0.f};

    float nsq = 0.f;
    float4 ra0, ra1, ra2, ra3, ra4, ra5, ra6, ra7;

    unsigned short *Ac = &As[0][0][0], *An = &As[1][0][0];
    unsigned short *Bc = &Bs[0][0][0], *Bn = &Bs[1][0][0];

    #define LOAD_A_LO(kt_) do {                                               \
        if (tvalid) {                                                         \
            const float4* p_ = (const float4*)(tgp + (kt_) * BK);             \
            ra0 = p_[0]; ra1 = p_[1]; ra2 = p_[2]; ra3 = p_[3];               \
        } else {                                                              \
            ra0 = ra1 = ra2 = ra3 = make_float4(0.f, 0.f, 0.f, 0.f);          \
        }                                                                     \
    } while (0)

    #define LOAD_A_HI(kt_) do {                                               \
        if (tvalid) {                                                         \
            const float4* p_ = (const float4*)(tgp + (kt_) * BK);             \
            ra4 = p_[4]; ra5 = p_[5]; ra6 = p_[6]; ra7 = p_[7];               \
        } else {                                                              \
            ra4 = ra5 = ra6 = ra7 = make_float4(0.f, 0.f, 0.f, 0.f);          \
        }                                                                     \
    } while (0)

    #define STAGE_B4(Bb_, kt_) do {                                           \
        const char* gp_ = srcb + (size_t)(kt_) * 131072 +                     \
                          (size_t)(c0 + w * 32) * 128 + (size_t)lane * 16;    \
        gload16(gp_,        (Bb_) + (w * 32 +  0) * BK);                      \
        gload16(gp_ + 1024, (Bb_) + (w * 32 +  8) * BK);                      \
        gload16(gp_ + 2048, (Bb_) + (w * 32 + 16) * BK);                      \
        gload16(gp_ + 3072, (Bb_) + (w * 32 + 24) * BK);                      \
    } while (0)

    #define PACK_WRITE_A(Ab_) do {                                            \
        nsq += ra0.x*ra0.x + ra0.y*ra0.y + ra0.z*ra0.z + ra0.w*ra0.w          \
             + ra1.x*ra1.x + ra1.y*ra1.y + ra1.z*ra1.z + ra1.w*ra1.w          \
             + ra2.x*ra2.x + ra2.y*ra2.y + ra2.z*ra2.z + ra2.w*ra2.w          \
             + ra3.x*ra3.x + ra3.y*ra3.y + ra3.z*ra3.z + ra3.w*ra3.w          \
             + ra4.x*ra4.x + ra4.y*ra4.y + ra4.z*ra4.z + ra4.w*ra4.w          \
             + ra5.x*ra5.x + ra5.y*ra5.y + ra5.z*ra5.z + ra5.w*ra5.w          \
             + ra6.x*ra6.x + ra6.y*ra6.y + ra6.z*ra6.z + ra6.w*ra6.w          \
             + ra7.x*ra7.x + ra7.y*ra7.y + ra7.z*ra7.z + ra7.w*ra7.w;         \
        u32x4 q0_ = { pack_trunc(ra0.x, ra0.y), pack_trunc(ra0.z, ra0.w),     \
                      pack_trunc(ra1.x, ra1.y), pack_trunc(ra1.z, ra1.w) };   \
        u32x4 q1_ = { pack_trunc(ra2.x, ra2.y), pack_trunc(ra2.z, ra2.w),     \
                      pack_trunc(ra3.x, ra3.y), pack_trunc(ra3.z, ra3.w) };   \
        u32x4 q2_ = { pack_trunc(ra4.x, ra4.y), pack_trunc(ra4.z, ra4.w),     \
                      pack_trunc(ra5.x, ra5.y), pack_trunc(ra5.z, ra5.w) };   \
        u32x4 q3_ = { pack_trunc(ra6.x, ra6.y), pack_trunc(ra6.z, ra6.w),     \
                      pack_trunc(ra7.x, ra7.y), pack_trunc(ra7.z, ra7.w) };   \
        *(u32x4*)((Ab_) + ra * BK + s0w * 8) = q0_;                           \
        *(u32x4*)((Ab_) + ra * BK + s1w * 8) = q1_;                           \
        *(u32x4*)((Ab_) + ra * BK + s2w * 8) = q2_;                           \
        *(u32x4*)((Ab_) + ra * BK + s3w * 8) = q3_;                           \
    } while (0)

    // frag read: content chunk (g + 4*kw) at LDS slot chunk^(row&7); frag
    // rows are base + mf*16 + li so row&7 == li&7 (lane-constant).
    #define READ_A4(dst_, hf_, kw_) do {                                      \
        const int sl_ = ((g + (kw_) * 4) ^ li7) * 8;                          \
        _Pragma("unroll")                                                     \
        for (int mf = 0; mf < 4; ++mf)                                        \
            dst_[mf] = *(const bf16x8*)(Ac +                                  \
                (wm * 128 + (hf_) * 64 + mf * 16 + li) * BK + sl_);           \
    } while (0)

    #define READ_B4(dst_, kw_) do {                                           \
        const int sl_ = ((g + (kw_) * 4) ^ li7) * 8;                          \
        _Pragma("unroll")                                                     \
        for (int nf = 0; nf < 4; ++nf)                                        \
            dst_[nf] = *(const bf16x8*)(Bc +                                  \
                (wn * 64 + nf * 16 + li) * BK + sl_);                         \
    } while (0)

    #define DO_MFMA(AF_, BF_, MB_) do {                                       \
        _Pragma("unroll")                                                     \
        for (int mf = 0; mf < 4; ++mf)                                        \
            _Pragma("unroll")                                                 \
            for (int nf = 0; nf < 4; ++nf)                                    \
                acc[(MB_) + mf][nf] = __builtin_amdgcn_mfma_f32_16x16x32_bf16(\
                    AF_[mf], BF_[nf], acc[(MB_) + mf][nf], 0, 0, 0);          \
    } while (0)

    #define BAR_PRE do {                                                      \
        __builtin_amdgcn_s_barrier();                                         \
        asm volatile("s_waitcnt lgkmcnt(0)" ::: "memory");                    \
        __builtin_amdgcn_sched_barrier(0);                                    \
        __builtin_amdgcn_s_setprio(1);                                        \
    } while (0)

    #define BAR_POST do {                                                     \
        __builtin_amdgcn_s_setprio(0);                                        \
        __builtin_amdgcn_s_barrier();                                         \
    } while (0)

    // ---- prologue: fill tile 0 (A via regs+pack, B via gload), drain, bar
    STAGE_B4(Bc, 0);
    LOAD_A_LO(0);
    LOAD_A_HI(0);
    PACK_WRITE_A(Ac);                 // compiler inserts the vmcnt for regs
    asm volatile("s_waitcnt vmcnt(0) lgkmcnt(0)" ::: "memory");
    __builtin_amdgcn_sched_barrier(0);
    __builtin_amdgcn_s_barrier();

    for (int kt = 0; kt < NKT; ++kt) {
        const bool pf = (kt + 1) < NKT;
        bf16x8 bf0[4], bf1[4];
        // ---- phase 0: frags (A lo, B kw0) + issue all next-tile loads
        {
            bf16x8 af[4];
            READ_A4(af, 0, 0);
            READ_B4(bf0, 0);
            if (pf) {
                STAGE_B4(Bn, kt + 1);
                LOAD_A_LO(kt + 1);
            }
            BAR_PRE;
            DO_MFMA(af, bf0, 0);
            BAR_POST;
        }
        // ---- phase 1: frags (A hi kw0) + remaining A loads
        {
            bf16x8 af[4];
            READ_A4(af, 1, 0);
            if (pf) LOAD_A_HI(kt + 1);
            BAR_PRE;
            DO_MFMA(af, bf0, 4);
            BAR_POST;
        }
        // ---- phase 2: frags (A lo kw1, B kw1)
        {
            bf16x8 af[4];
            READ_A4(af, 0, 1);
            READ_B4(bf1, 1);
            BAR_PRE;
            DO_MFMA(af, bf1, 0);
            BAR_POST;
        }
        // ---- phase 3: frags (A hi kw1) + pack/write next A + drain vmem
        {
            bf16x8 af[4];
            READ_A4(af, 1, 1);
            if (pf) {
                PACK_WRITE_A(An);
                asm volatile("s_waitcnt vmcnt(0)" ::: "memory");
                __builtin_amdgcn_sched_barrier(0);
            }
            BAR_PRE;
            DO_MFMA(af, bf1, 4);
            BAR_POST;
        }
        // swap buffers
        unsigned short* tmp_;
        tmp_ = Ac; Ac = An; An = tmp_;
        tmp_ = Bc; Bc = Bn; Bn = tmp_;
    }

    // ---- in-block target inverse norms (exact f32)
    nsq_sh[t] = nsq;
    __syncthreads();
    if (t < TB) {
        float s = nsq_sh[2 * t] + nsq_sh[2 * t + 1];
        invn_sh[t] = ((m0 + t) < N_TGT) ? 1.0f / sqrtf(s) : -1.0f;
    }
    __syncthreads();

    // ---- epilogue: scale, per-source-column top-4 over the wave's 128 rows
    float invr[8][4];
    #pragma unroll
    for (int mf = 0; mf < 8; ++mf)
        #pragma unroll
        for (int j = 0; j < 4; ++j)
            invr[mf][j] = invn_sh[wm * 128 + mf * 16 + g * 4 + j];

    const int strip = mblk * 2 + wm;
    #pragma unroll
    for (int nf = 0; nf < 4; ++nf) {
        const int scol = c0 + wn * 64 + nf * 16 + li;
        float s[8][4];
        #pragma unroll
        for (int mf = 0; mf < 8; ++mf)
            #pragma unroll
            for (int j = 0; j < 4; ++j)
                s[mf][j] = (invr[mf][j] > 0.f) ? acc[mf][nf][j] * invr[mf][j]
                                               : -FLT_MAX;
        #pragma unroll
        for (int it = 0; it < KNN; ++it) {
            float bv = -FLT_MAX; int bli = 0;
            #pragma unroll
            for (int mf = 0; mf < 8; ++mf)
                #pragma unroll
                for (int j = 0; j < 4; ++j) {
                    int id = mf * 16 + g * 4 + j;
                    if (s[mf][j] > bv) { bv = s[mf][j]; bli = id; }
                }
            #pragma unroll
            for (int off = 16; off < 64; off <<= 1) {
                float ov = __shfl_xor(bv, off);
                int   oi = __shfl_xor(bli, off);
                if (ov > bv || (ov == bv && oi < bli)) { bv = ov; bli = oi; }
            }
            const int mfw = bli >> 4, gw = (bli >> 2) & 3, jw = bli & 3;
            if (g == gw) {
                #pragma unroll
                for (int mf = 0; mf < 8; ++mf)
                    #pragma unroll
                    for (int j = 0; j < 4; ++j)
                        if (mf == mfw && j == jw) s[mf][j] = -FLT_MAX;
            }
            if (g == it) {
                size_t o = ((size_t)scol * NSTRIP + strip) * KNN + it;
                cand_val[o] = bv;
                cand_idx[o] = m0 + wm * 128 + bli;
            }
        }
    }
}

// ---------------------------------------------------------------------------
// Kernel 3: per source row — candidate top-16, exact f32 rerank, top-4,
// gather + mean. One block (256 thr) per row.
// ---------------------------------------------------------------------------
__global__ __launch_bounds__(256) void merge_rerank_kernel(
    const float* __restrict__ src, const float* __restrict__ tgt,
    const float* __restrict__ cand_val, const int* __restrict__ cand_idx,
    float* __restrict__ out)
{
    __shared__ float sv[NCAND];          // 12.5 KB
    __shared__ float red_v[4];
    __shared__ int   red_p[4];
    __shared__ int   topi[RERANK];
    __shared__ float rsim[RERANK];
    __shared__ int   ridx[RERANK];
    __shared__ int   sel[KNN];

    const int row = blockIdx.x;
    const int t = threadIdx.x, lane = t & 63, w = t >> 6;
    const float* cv = cand_val + (size_t)row * NCAND;
    const int*   ci = cand_idx + (size_t)row * NCAND;

    for (int i = t; i < NCAND; i += 256) sv[i] = cv[i];
    __syncthreads();

    for (int it = 0; it < RERANK; ++it) {
        float bv = -FLT_MAX; int bp = 0;
        for (int i = t; i < NCAND; i += 256) {
            float v = sv[i];
            if (v > bv) { bv = v; bp = i; }
        }
        #pragma unroll
        for (int off = 1; off < 64; off <<= 1) {
            float ov = __shfl_xor(bv, off);
            int   op = __shfl_xor(bp, off);
            if (ov > bv || (ov == bv && op < bp)) { bv = ov; bp = op; }
        }
        if (lane == 0) { red_v[w] = bv; red_p[w] = bp; }
        __syncthreads();
        if (t == 0) {
            float Bv = red_v[0]; int Bp = red_p[0];
            for (int q = 1; q < 4; ++q)
                if (red_v[q] > Bv || (red_v[q] == Bv && red_p[q] < Bp)) {
                    Bv = red_v[q]; Bp = red_p[q];
                }
            topi[it] = ci[Bp];
            sv[Bp] = -FLT_MAX;
        }
        __syncthreads();
    }

    // exact f32 rerank: dot AND target norm from the same row read
    const float4* sp = (const float4*)(src + (size_t)row * DIM);
    #pragma unroll
    for (int q = 0; q < 4; ++q) {
        int cidx = topi[w + 4 * q];
        const float4* tp = (const float4*)(tgt + (size_t)cidx * DIM);
        float a = 0.f, nn = 0.f;
        #pragma unroll
        for (int p = 0; p < 4; ++p) {
            float4 x = sp[lane + 64 * p], y = tp[lane + 64 * p];
            a  = fmaf(x.x, y.x, a);  a  = fmaf(x.y, y.y, a);
            a  = fmaf(x.z, y.z, a);  a  = fmaf(x.w, y.w, a);
            nn = fmaf(y.x, y.x, nn); nn = fmaf(y.y, y.y, nn);
            nn = fmaf(y.z, y.z, nn); nn = fmaf(y.w, y.w, nn);
        }
        #pragma unroll
        for (int off = 1; off < 64; off <<= 1) {
            a  += __shfl_xor(a, off);
            nn += __shfl_xor(nn, off);
        }
        if (lane == 0) { rsim[w + 4 * q] = a / sqrtf(nn); ridx[w + 4 * q] = cidx; }
    }
    __syncthreads();

    if (w == 0) {
        float v = (lane < RERANK) ? rsim[lane] : -FLT_MAX;
        int  ix = (lane < RERANK) ? ridx[lane] : 0x7fffffff;
        #pragma unroll
        for (int it = 0; it < KNN; ++it) {
            float bv = v; int bix = ix;
            #pragma unroll
            for (int off = 1; off < 16; off <<= 1) {
                float ov = __shfl_xor(bv, off);
                int   oi = __shfl_xor(bix, off);
                if (ov > bv || (ov == bv && oi < bix)) { bv = ov; bix = oi; }
            }
            if (lane == 0) sel[it] = bix;
            if (ix == bix) v = -FLT_MAX;
        }
    }
    __syncthreads();

    const float4* g0 = (const float4*)(tgt + (size_t)sel[0] * DIM);
    const float4* g1 = (const float4*)(tgt + (size_t)sel[1] * DIM);
    const float4* g2 = (const float4*)(tgt + (size_t)sel[2] * DIM);
    const float4* g3 = (const float4*)(tgt + (size_t)sel[3] * DIM);
    float4* po = (float4*)(out + (size_t)row * DIM);
    float4 v0 = g0[t], v1 = g1[t], v2 = g2[t], v3 = g3[t];
    float4 rr;
    rr.x = (v0.x + v1.x + v2.x + v3.x) * 0.25f;
    rr.y = (v0.y + v1.y + v2.y + v3.y) * 0.25f;
    rr.z = (v0.z + v1.z + v2.z + v3.z) * 0.25f;
    rr.w = (v0.w + v1.w + v2.w + v3.w) * 0.25f;
    po[t] = rr;
}

// ---------------------------------------------------------------------------
extern "C" void kernel_launch(void* const* d_in, const int* in_sizes, int n_in,
                              void* d_out, int out_size, void* d_ws, size_t ws_size,
                              hipStream_t stream)
{
    const float* src = (const float*)d_in[0];
    const float* tgt = (const float*)d_in[1];
    float* out = (float*)d_out;

    // ws: srcws bf16 pre-swizzled [2 MB] | cand_val [12.8 MB] | cand_idx [12.8 MB]
    unsigned int* srcws = (unsigned int*)d_ws;
    float* cand_val = (float*)((char*)d_ws + (2u << 20));
    int*   cand_idx = (int*)(cand_val + (size_t)N_SRC * NCAND);

    convert_src_kernel<<<512, 256, 0, stream>>>(src, srcws);

    gemm_topk_kernel<<<NBLK, 512, 0, stream>>>(tgt, srcws, cand_val, cand_idx);

    merge_rerank_kernel<<<N_SRC, 256, 0, stream>>>(src, tgt,
                                                   cand_val, cand_idx, out);
}

// Round 6
// 483.236 us; speedup vs baseline: 1.2235x; 1.1045x over previous
//
#include <hip/hip_runtime.h>
#include <hip/hip_bf16.h>
#include <float.h>

#define N_SRC 1024
#define N_TGT 100000
#define DIM   1024
#define KNN   4

// GEMM geometry: M = targets (256/block), N = sources (256/block), BK=64.
#define TB 256
#define SBn 256
#define BK 64
#define NKT (DIM / BK)               // 16 K-tiles
#define NMB 391                      // target panels (391*256 = 100096)
#define N_TGT2 (NMB * TB)            // 100096 padded target rows
#define NSC (N_SRC / SBn)            // 4 source chunks
#define NBLK (NMB * NSC)             // 1564
#define NSTRIP (NMB * 2)             // 782 strips of 128 rows
#define NCAND (NSTRIP * KNN)         // 3128 candidates per source row
#define RERANK 16

#define SRC_KT_B 131072ull                              // src ws bytes per kt
#define TGT_KT_B ((unsigned long long)N_TGT2 * 128ull)  // tgt ws bytes per kt

typedef __attribute__((ext_vector_type(8))) short bf16x8;
typedef __attribute__((ext_vector_type(4))) float f32x4;
typedef __attribute__((ext_vector_type(4))) unsigned int u32x4;

// bf16 truncation pack: one v_perm_b32 for two floats (a = lower k index).
__device__ __forceinline__ unsigned int pack_trunc(float a, float b) {
    return __builtin_amdgcn_perm(__builtin_bit_cast(unsigned int, b),
                                 __builtin_bit_cast(unsigned int, a),
                                 0x07060302u);
}

__device__ __forceinline__ void gload16(const void* gp, void* lp) {
    __builtin_amdgcn_global_load_lds(
        (const __attribute__((address_space(1))) void*)gp,
        (__attribute__((address_space(3))) void*)lp, 16, 0, 0);
}

// ---------------------------------------------------------------------------
// Kernel 1: sources f32 -> bf16 ws, layout [kt][1024 rows][8 slots x 16B],
// slot swizzle pre-applied: position (row, s) holds k-chunk (s ^ (row&7)).
// ---------------------------------------------------------------------------
__global__ __launch_bounds__(256) void convert_src_kernel(
    const float* __restrict__ src, unsigned int* __restrict__ srcws)
{
    int gid = blockIdx.x * 256 + threadIdx.x;   // 16B chunk id; 131072 total
    int kt  = gid >> 13;
    int rem = gid & 8191;
    int row = rem >> 3;
    int s   = rem & 7;
    int c   = s ^ (row & 7);
    const float4* p = (const float4*)(src + (size_t)row * DIM + kt * 64 + c * 8);
    float4 a = p[0], b = p[1];
    u32x4 o = { pack_trunc(a.x, a.y), pack_trunc(a.z, a.w),
                pack_trunc(b.x, b.y), pack_trunc(b.z, b.w) };
    ((u32x4*)srcws)[gid] = o;
}

// ---------------------------------------------------------------------------
// Kernel 1b: targets f32 -> bf16 ws in the same pre-swizzled layout
// [kt][N_TGT2 rows][8 x 16B granules], PLUS exact f32 inverse norms.
// Thread t: row = blk*16 + (t&15), kt = t>>4 (one 64-k window per thread).
// ---------------------------------------------------------------------------
__global__ __launch_bounds__(256) void prep_tgt_kernel(
    const float* __restrict__ tgt, unsigned int* __restrict__ tgtbf,
    float* __restrict__ invnw)
{
    __shared__ float pn[16][17];
    const int t  = threadIdx.x;
    const int li = t & 15;
    const int kt = t >> 4;
    const int row = blockIdx.x * 16 + li;
    const bool valid = row < N_TGT;

    float4 v[16];
    if (valid) {
        const float4* p = (const float4*)(tgt + (size_t)row * DIM + kt * 64);
        #pragma unroll
        for (int i = 0; i < 16; ++i) v[i] = p[i];
    } else {
        #pragma unroll
        for (int i = 0; i < 16; ++i) v[i] = make_float4(0.f, 0.f, 0.f, 0.f);
    }
    float nsq = 0.f;
    #pragma unroll
    for (int i = 0; i < 16; ++i)
        nsq += v[i].x * v[i].x + v[i].y * v[i].y
             + v[i].z * v[i].z + v[i].w * v[i].w;

    // content chunk c (static index into v) stored at slot c ^ (row&7)
    u32x4* o = (u32x4*)((char*)tgtbf + (size_t)kt * TGT_KT_B
                        + (size_t)row * 128);
    const int r7 = row & 7;
    #pragma unroll
    for (int c = 0; c < 8; ++c) {
        float4 a = v[2 * c], b2 = v[2 * c + 1];
        o[c ^ r7] = (u32x4){ pack_trunc(a.x, a.y), pack_trunc(a.z, a.w),
                             pack_trunc(b2.x, b2.y), pack_trunc(b2.z, b2.w) };
    }

    pn[li][kt] = nsq;
    __syncthreads();
    if (t < 16) {
        float s = 0.f;
        #pragma unroll
        for (int k = 0; k < 16; ++k) s += pn[t][k];
        int r2 = blockIdx.x * 16 + t;
        invnw[r2] = (r2 < N_TGT) ? 1.0f / sqrtf(s) : -1.0f;
    }
}

// ---------------------------------------------------------------------------
// Kernel 2 (big-ws path): pure-bf16 256x256 MFMA GEMM. Both operands staged
// by global_load_lds from pre-swizzled ws (zero staging VALU), 4 phases per
// K-tile, 16 MFMA each, double-buffered LDS. Epilogue: per-source-column
// top-4 over the wave's 128 target rows.
// ---------------------------------------------------------------------------
__global__ __launch_bounds__(512, 2) void gemm_topk_bf_kernel(
    const void* __restrict__ tgtbf, const void* __restrict__ srcbf,
    const float* __restrict__ invnw,
    float* __restrict__ cand_val, int* __restrict__ cand_idx)
{
    __shared__ __align__(16) unsigned short As[2][TB][BK];   // 64 KB
    __shared__ __align__(16) unsigned short Bs[2][SBn][BK];  // 64 KB
    __shared__ float invn_sh[TB];

    const int b   = blockIdx.x;
    const int xcd = b & 7, sub = b >> 3;
    const int base = (xcd < 4) ? xcd * 196 : 4 * 196 + (xcd - 4) * 195;
    const int logical = base + sub;
    const int mblk = logical >> 2;
    const int schk = logical & 3;
    const int m0 = mblk * TB;
    const int c0 = schk * SBn;

    const int t = threadIdx.x;
    const int lane = t & 63;
    const int w = t >> 6;
    const int wm = w >> 2, wn = w & 3;      // 2M x 4N, per-wave 128x64
    const int g = lane >> 4, li = lane & 15;
    const int li7 = li & 7;

    const char* tb = (const char*)tgtbf;
    const char* sb = (const char*)srcbf;

    f32x4 acc[8][4];
    #pragma unroll
    for (int i = 0; i < 8; ++i)
        #pragma unroll
        for (int j = 0; j < 4; ++j) acc[i][j] = (f32x4){0.f, 0.f, 0.f, 0.f};

    unsigned short *Ac = &As[0][0][0], *An = &As[1][0][0];
    unsigned short *Bc = &Bs[0][0][0], *Bn = &Bs[1][0][0];

    #define STAGE_A4(Ab_, kt_) do {                                           \
        const char* gp_ = tb + (size_t)(kt_) * TGT_KT_B +                     \
                          (size_t)(m0 + w * 32) * 128 + (size_t)lane * 16;    \
        gload16(gp_,        (Ab_) + (w * 32 +  0) * BK);                      \
        gload16(gp_ + 1024, (Ab_) + (w * 32 +  8) * BK);                      \
        gload16(gp_ + 2048, (Ab_) + (w * 32 + 16) * BK);                      \
        gload16(gp_ + 3072, (Ab_) + (w * 32 + 24) * BK);                      \
    } while (0)

    #define STAGE_B4(Bb_, kt_) do {                                           \
        const char* gp_ = sb + (size_t)(kt_) * SRC_KT_B +                     \
                          (size_t)(c0 + w * 32) * 128 + (size_t)lane * 16;    \
        gload16(gp_,        (Bb_) + (w * 32 +  0) * BK);                      \
        gload16(gp_ + 1024, (Bb_) + (w * 32 +  8) * BK);                      \
        gload16(gp_ + 2048, (Bb_) + (w * 32 + 16) * BK);                      \
        gload16(gp_ + 3072, (Bb_) + (w * 32 + 24) * BK);                      \
    } while (0)

    #define READ_A4(dst_, hf_, kw_) do {                                      \
        const int sl_ = ((g + (kw_) * 4) ^ li7) * 8;                          \
        _Pragma("unroll")                                                     \
        for (int mf = 0; mf < 4; ++mf)                                        \
            dst_[mf] = *(const bf16x8*)(Ac +                                  \
                (wm * 128 + (hf_) * 64 + mf * 16 + li) * BK + sl_);           \
    } while (0)

    #define READ_B4(dst_, kw_) do {                                           \
        const int sl_ = ((g + (kw_) * 4) ^ li7) * 8;                          \
        _Pragma("unroll")                                                     \
        for (int nf = 0; nf < 4; ++nf)                                        \
            dst_[nf] = *(const bf16x8*)(Bc +                                  \
                (wn * 64 + nf * 16 + li) * BK + sl_);                         \
    } while (0)

    #define DO_MFMA(AF_, BF_, MB_) do {                                       \
        _Pragma("unroll")                                                     \
        for (int mf = 0; mf < 4; ++mf)                                        \
            _Pragma("unroll")                                                 \
            for (int nf = 0; nf < 4; ++nf)                                    \
                acc[(MB_) + mf][nf] = __builtin_amdgcn_mfma_f32_16x16x32_bf16(\
                    AF_[mf], BF_[nf], acc[(MB_) + mf][nf], 0, 0, 0);          \
    } while (0)

    #define BAR_PRE do {                                                      \
        __builtin_amdgcn_s_barrier();                                         \
        asm volatile("s_waitcnt lgkmcnt(0)" ::: "memory");                    \
        __builtin_amdgcn_sched_barrier(0);                                    \
        __builtin_amdgcn_s_setprio(1);                                        \
    } while (0)

    #define BAR_POST do {                                                     \
        __builtin_amdgcn_s_setprio(0);                                        \
        __builtin_amdgcn_s_barrier();                                         \
    } while (0)

    // ---- prologue: stage tile 0, drain, barrier
    STAGE_A4(Ac, 0);
    STAGE_B4(Bc, 0);
    asm volatile("s_waitcnt vmcnt(0)" ::: "memory");
    __builtin_amdgcn_sched_barrier(0);
    __builtin_amdgcn_s_barrier();

    for (int kt = 0; kt < NKT; ++kt) {
        const bool pf = (kt + 1) < NKT;
        bf16x8 bf0[4], bf1[4];
        // ---- phase 0: frags (A lo kw0, B kw0) + stage next A
        {
            bf16x8 af[4];
            READ_A4(af, 0, 0);
            READ_B4(bf0, 0);
            if (pf) STAGE_A4(An, kt + 1);
            BAR_PRE;
            DO_MFMA(af, bf0, 0);
            BAR_POST;
        }
        // ---- phase 1: frags (A hi kw0) + stage next B
        {
            bf16x8 af[4];
            READ_A4(af, 1, 0);
            if (pf) STAGE_B4(Bn, kt + 1);
            BAR_PRE;
            DO_MFMA(af, bf0, 4);
            BAR_POST;
        }
        // ---- phase 2: frags (A lo kw1, B kw1)
        {
            bf16x8 af[4];
            READ_A4(af, 0, 1);
            READ_B4(bf1, 1);
            BAR_PRE;
            DO_MFMA(af, bf1, 0);
            BAR_POST;
        }
        // ---- phase 3: frags (A hi kw1) + drain next-tile loads
        {
            bf16x8 af[4];
            READ_A4(af, 1, 1);
            if (pf) {
                asm volatile("s_waitcnt vmcnt(0)" ::: "memory");
                __builtin_amdgcn_sched_barrier(0);
            }
            BAR_PRE;
            DO_MFMA(af, bf1, 4);
            BAR_POST;
        }
        unsigned short* tmp_;
        tmp_ = Ac; Ac = An; An = tmp_;
        tmp_ = Bc; Bc = Bn; Bn = tmp_;
    }
    #undef STAGE_A4
    #undef STAGE_B4
    #undef READ_A4
    #undef READ_B4
    #undef DO_MFMA
    #undef BAR_PRE
    #undef BAR_POST

    // ---- epilogue: exact f32 invn from prep pass
    if (t < TB) invn_sh[t] = invnw[m0 + t];
    __syncthreads();

    float invr[8][4];
    #pragma unroll
    for (int mf = 0; mf < 8; ++mf)
        #pragma unroll
        for (int j = 0; j < 4; ++j)
            invr[mf][j] = invn_sh[wm * 128 + mf * 16 + g * 4 + j];

    const int strip = mblk * 2 + wm;
    #pragma unroll
    for (int nf = 0; nf < 4; ++nf) {
        const int scol = c0 + wn * 64 + nf * 16 + li;
        float s[8][4];
        #pragma unroll
        for (int mf = 0; mf < 8; ++mf)
            #pragma unroll
            for (int j = 0; j < 4; ++j)
                s[mf][j] = (invr[mf][j] > 0.f) ? acc[mf][nf][j] * invr[mf][j]
                                               : -FLT_MAX;
        #pragma unroll
        for (int it = 0; it < KNN; ++it) {
            float bv = -FLT_MAX; int bli = 0;
            #pragma unroll
            for (int mf = 0; mf < 8; ++mf)
                #pragma unroll
                for (int j = 0; j < 4; ++j) {
                    int id = mf * 16 + g * 4 + j;
                    if (s[mf][j] > bv) { bv = s[mf][j]; bli = id; }
                }
            #pragma unroll
            for (int off = 16; off < 64; off <<= 1) {
                float ov = __shfl_xor(bv, off);
                int   oi = __shfl_xor(bli, off);
                if (ov > bv || (ov == bv && oi < bli)) { bv = ov; bli = oi; }
            }
            const int mfw = bli >> 4, gw = (bli >> 2) & 3, jw = bli & 3;
            if (g == gw) {
                #pragma unroll
                for (int mf = 0; mf < 8; ++mf)
                    #pragma unroll
                    for (int j = 0; j < 4; ++j)
                        if (mf == mfw && j == jw) s[mf][j] = -FLT_MAX;
            }
            if (g == it) {
                size_t o = ((size_t)scol * NSTRIP + strip) * KNN + it;
                cand_val[o] = bv;
                cand_idx[o] = m0 + wm * 128 + bli;
            }
        }
    }
}

// ---------------------------------------------------------------------------
// Kernel 2' (fallback path, ws too small): round-5 GEMM verbatim
// (in-loop f32 A staging + pack + in-block norms).
// ---------------------------------------------------------------------------
__global__ __launch_bounds__(512, 2) void gemm_topk_old_kernel(
    const float* __restrict__ tgt, const void* __restrict__ srcws,
    float* __restrict__ cand_val, int* __restrict__ cand_idx)
{
    __shared__ __align__(16) unsigned short As[2][TB][BK];   // 64 KB
    __shared__ __align__(16) unsigned short Bs[2][SBn][BK];  // 64 KB
    __shared__ float nsq_sh[512];
    __shared__ float invn_sh[TB];

    const int b   = blockIdx.x;
    const int xcd = b & 7, sub = b >> 3;
    const int base = (xcd < 4) ? xcd * 196 : 4 * 196 + (xcd - 4) * 195;
    const int logical = base + sub;
    const int mblk = logical >> 2;
    const int schk = logical & 3;
    const int m0 = mblk * TB;
    const int c0 = schk * SBn;

    const int t = threadIdx.x;
    const int lane = t & 63;
    const int w = t >> 6;
    const int wm = w >> 2, wn = w & 3;
    const int g = lane >> 4, li = lane & 15;
    const int li7 = li & 7;

    const int ra = t >> 1;
    const int h  = t & 1;
    const int s0w = (4 * h + 0) ^ (ra & 7);
    const int s1w = (4 * h + 1) ^ (ra & 7);
    const int s2w = (4 * h + 2) ^ (ra & 7);
    const int s3w = (4 * h + 3) ^ (ra & 7);
    const bool tvalid = (m0 + ra) < N_TGT;
    const float* tgp = tgt + (size_t)(m0 + ra) * DIM + h * 32;

    const char* srcb = (const char*)srcws;

    f32x4 acc[8][4];
    #pragma unroll
    for (int i = 0; i < 8; ++i)
        #pragma unroll
        for (int j = 0; j < 4; ++j) acc[i][j] = (f32x4){0.f, 0.f, 0.f, 0.f};

    float nsq = 0.f;
    float4 ra0, ra1, ra2, ra3, ra4, ra5, ra6, ra7;

    unsigned short *Ac = &As[0][0][0], *An = &As[1][0][0];
    unsigned short *Bc = &Bs[0][0][0], *Bn = &Bs[1][0][0];

    #define LOAD_A_LO(kt_) do {                                               \
        if (tvalid) {                                                         \
            const float4* p_ = (const float4*)(tgp + (kt_) * BK);             \
            ra0 = p_[0]; ra1 = p_[1]; ra2 = p_[2]; ra3 = p_[3];               \
        } else {                                                              \
            ra0 = ra1 = ra2 = ra3 = make_float4(0.f, 0.f, 0.f, 0.f);          \
        }                                                                     \
    } while (0)

    #define LOAD_A_HI(kt_) do {                                               \
        if (tvalid) {                                                         \
            const float4* p_ = (const float4*)(tgp + (kt_) * BK);             \
            ra4 = p_[4]; ra5 = p_[5]; ra6 = p_[6]; ra7 = p_[7];               \
        } else {                                                              \
            ra4 = ra5 = ra6 = ra7 = make_float4(0.f, 0.f, 0.f, 0.f);          \
        }                                                                     \
    } while (0)

    #define STAGE_B4O(Bb_, kt_) do {                                          \
        const char* gp_ = srcb + (size_t)(kt_) * SRC_KT_B +                   \
                          (size_t)(c0 + w * 32) * 128 + (size_t)lane * 16;    \
        gload16(gp_,        (Bb_) + (w * 32 +  0) * BK);                      \
        gload16(gp_ + 1024, (Bb_) + (w * 32 +  8) * BK);                      \
        gload16(gp_ + 2048, (Bb_) + (w * 32 + 16) * BK);                      \
        gload16(gp_ + 3072, (Bb_) + (w * 32 + 24) * BK);                      \
    } while (0)

    #define PACK_WRITE_A(Ab_) do {                                            \
        nsq += ra0.x*ra0.x + ra0.y*ra0.y + ra0.z*ra0.z + ra0.w*ra0.w          \
             + ra1.x*ra1.x + ra1.y*ra1.y + ra1.z*ra1.z + ra1.w*ra1.w          \
             + ra2.x*ra2.x + ra2.y*ra2.y + ra2.z*ra2.z + ra2.w*ra2.w          \
             + ra3.x*ra3.x + ra3.y*ra3.y + ra3.z*ra3.z + ra3.w*ra3.w          \
             + ra4.x*ra4.x + ra4.y*ra4.y + ra4.z*ra4.z + ra4.w*ra4.w          \
             + ra5.x*ra5.x + ra5.y*ra5.y + ra5.z*ra5.z + ra5.w*ra5.w          \
             + ra6.x*ra6.x + ra6.y*ra6.y + ra6.z*ra6.z + ra6.w*ra6.w          \
             + ra7.x*ra7.x + ra7.y*ra7.y + ra7.z*ra7.z + ra7.w*ra7.w;         \
        u32x4 q0_ = { pack_trunc(ra0.x, ra0.y), pack_trunc(ra0.z, ra0.w),     \
                      pack_trunc(ra1.x, ra1.y), pack_trunc(ra1.z, ra1.w) };   \
        u32x4 q1_ = { pack_trunc(ra2.x, ra2.y), pack_trunc(ra2.z, ra2.w),     \
                      pack_trunc(ra3.x, ra3.y), pack_trunc(ra3.z, ra3.w) };   \
        u32x4 q2_ = { pack_trunc(ra4.x, ra4.y), pack_trunc(ra4.z, ra4.w),     \
                      pack_trunc(ra5.x, ra5.y), pack_trunc(ra5.z, ra5.w) };   \
        u32x4 q3_ = { pack_trunc(ra6.x, ra6.y), pack_trunc(ra6.z, ra6.w),     \
                      pack_trunc(ra7.x, ra7.y), pack_trunc(ra7.z, ra7.w) };   \
        *(u32x4*)((Ab_) + ra * BK + s0w * 8) = q0_;                           \
        *(u32x4*)((Ab_) + ra * BK + s1w * 8) = q1_;                           \
        *(u32x4*)((Ab_) + ra * BK + s2w * 8) = q2_;                           \
        *(u32x4*)((Ab_) + ra * BK + s3w * 8) = q3_;                           \
    } while (0)

    #define READ_A4O(dst_, hf_, kw_) do {                                     \
        const int sl_ = ((g + (kw_) * 4) ^ li7) * 8;                          \
        _Pragma("unroll")                                                     \
        for (int mf = 0; mf < 4; ++mf)                                        \
            dst_[mf] = *(const bf16x8*)(Ac +                                  \
                (wm * 128 + (hf_) * 64 + mf * 16 + li) * BK + sl_);           \
    } while (0)

    #define READ_B4O(dst_, kw_) do {                                          \
        const int sl_ = ((g + (kw_) * 4) ^ li7) * 8;                          \
        _Pragma("unroll")                                                     \
        for (int nf = 0; nf < 4; ++nf)                                        \
            dst_[nf] = *(const bf16x8*)(Bc +                                  \
                (wn * 64 + nf * 16 + li) * BK + sl_);                         \
    } while (0)

    #define DO_MFMAO(AF_, BF_, MB_) do {                                      \
        _Pragma("unroll")                                                     \
        for (int mf = 0; mf < 4; ++mf)                                        \
            _Pragma("unroll")                                                 \
            for (int nf = 0; nf < 4; ++nf)                                    \
                acc[(MB_) + mf][nf] = __builtin_amdgcn_mfma_f32_16x16x32_bf16(\
                    AF_[mf], BF_[nf], acc[(MB_) + mf][nf], 0, 0, 0);          \
    } while (0)

    #define BAR_PREO do {                                                     \
        __builtin_amdgcn_s_barrier();                                         \
        asm volatile("s_waitcnt lgkmcnt(0)" ::: "memory");                    \
        __builtin_amdgcn_sched_barrier(0);                                    \
        __builtin_amdgcn_s_setprio(1);                                        \
    } while (0)

    #define BAR_POSTO do {                                                    \
        __builtin_amdgcn_s_setprio(0);                                        \
        __builtin_amdgcn_s_barrier();                                         \
    } while (0)

    STAGE_B4O(Bc, 0);
    LOAD_A_LO(0);
    LOAD_A_HI(0);
    PACK_WRITE_A(Ac);
    asm volatile("s_waitcnt vmcnt(0) lgkmcnt(0)" ::: "memory");
    __builtin_amdgcn_sched_barrier(0);
    __builtin_amdgcn_s_barrier();

    for (int kt = 0; kt < NKT; ++kt) {
        const bool pf = (kt + 1) < NKT;
        bf16x8 bf0[4], bf1[4];
        {
            bf16x8 af[4];
            READ_A4O(af, 0, 0);
            READ_B4O(bf0, 0);
            if (pf) {
                STAGE_B4O(Bn, kt + 1);
                LOAD_A_LO(kt + 1);
            }
            BAR_PREO;
            DO_MFMAO(af, bf0, 0);
            BAR_POSTO;
        }
        {
            bf16x8 af[4];
            READ_A4O(af, 1, 0);
            if (pf) LOAD_A_HI(kt + 1);
            BAR_PREO;
            DO_MFMAO(af, bf0, 4);
            BAR_POSTO;
        }
        {
            bf16x8 af[4];
            READ_A4O(af, 0, 1);
            READ_B4O(bf1, 1);
            BAR_PREO;
            DO_MFMAO(af, bf1, 0);
            BAR_POSTO;
        }
        {
            bf16x8 af[4];
            READ_A4O(af, 1, 1);
            if (pf) {
                PACK_WRITE_A(An);
                asm volatile("s_waitcnt vmcnt(0)" ::: "memory");
                __builtin_amdgcn_sched_barrier(0);
            }
            BAR_PREO;
            DO_MFMAO(af, bf1, 4);
            BAR_POSTO;
        }
        unsigned short* tmp_;
        tmp_ = Ac; Ac = An; An = tmp_;
        tmp_ = Bc; Bc = Bn; Bn = tmp_;
    }

    nsq_sh[t] = nsq;
    __syncthreads();
    if (t < TB) {
        float s = nsq_sh[2 * t] + nsq_sh[2 * t + 1];
        invn_sh[t] = ((m0 + t) < N_TGT) ? 1.0f / sqrtf(s) : -1.0f;
    }
    __syncthreads();

    float invr[8][4];
    #pragma unroll
    for (int mf = 0; mf < 8; ++mf)
        #pragma unroll
        for (int j = 0; j < 4; ++j)
            invr[mf][j] = invn_sh[wm * 128 + mf * 16 + g * 4 + j];

    const int strip = mblk * 2 + wm;
    #pragma unroll
    for (int nf = 0; nf < 4; ++nf) {
        const int scol = c0 + wn * 64 + nf * 16 + li;
        float s[8][4];
        #pragma unroll
        for (int mf = 0; mf < 8; ++mf)
            #pragma unroll
            for (int j = 0; j < 4; ++j)
                s[mf][j] = (invr[mf][j] > 0.f) ? acc[mf][nf][j] * invr[mf][j]
                                               : -FLT_MAX;
        #pragma unroll
        for (int it = 0; it < KNN; ++it) {
            float bv = -FLT_MAX; int bli = 0;
            #pragma unroll
            for (int mf = 0; mf < 8; ++mf)
                #pragma unroll
                for (int j = 0; j < 4; ++j) {
                    int id = mf * 16 + g * 4 + j;
                    if (s[mf][j] > bv) { bv = s[mf][j]; bli = id; }
                }
            #pragma unroll
            for (int off = 16; off < 64; off <<= 1) {
                float ov = __shfl_xor(bv, off);
                int   oi = __shfl_xor(bli, off);
                if (ov > bv || (ov == bv && oi < bli)) { bv = ov; bli = oi; }
            }
            const int mfw = bli >> 4, gw = (bli >> 2) & 3, jw = bli & 3;
            if (g == gw) {
                #pragma unroll
                for (int mf = 0; mf < 8; ++mf)
                    #pragma unroll
                    for (int j = 0; j < 4; ++j)
                        if (mf == mfw && j == jw) s[mf][j] = -FLT_MAX;
            }
            if (g == it) {
                size_t o = ((size_t)scol * NSTRIP + strip) * KNN + it;
                cand_val[o] = bv;
                cand_idx[o] = m0 + wm * 128 + bli;
            }
        }
    }
}

// ---------------------------------------------------------------------------
// Kernel 3: per source row — candidate top-16, exact f32 rerank, top-4,
// gather + mean. One block (256 thr) per row.
// ---------------------------------------------------------------------------
__global__ __launch_bounds__(256) void merge_rerank_kernel(
    const float* __restrict__ src, const float* __restrict__ tgt,
    const float* __restrict__ cand_val, const int* __restrict__ cand_idx,
    float* __restrict__ out)
{
    __shared__ float sv[NCAND];
    __shared__ float red_v[4];
    __shared__ int   red_p[4];
    __shared__ int   topi[RERANK];
    __shared__ float rsim[RERANK];
    __shared__ int   ridx[RERANK];
    __shared__ int   sel[KNN];

    const int row = blockIdx.x;
    const int t = threadIdx.x, lane = t & 63, w = t >> 6;
    const float* cv = cand_val + (size_t)row * NCAND;
    const int*   ci = cand_idx + (size_t)row * NCAND;

    for (int i = t; i < NCAND; i += 256) sv[i] = cv[i];
    __syncthreads();

    for (int it = 0; it < RERANK; ++it) {
        float bv = -FLT_MAX; int bp = 0;
        for (int i = t; i < NCAND; i += 256) {
            float v = sv[i];
            if (v > bv) { bv = v; bp = i; }
        }
        #pragma unroll
        for (int off = 1; off < 64; off <<= 1) {
            float ov = __shfl_xor(bv, off);
            int   op = __shfl_xor(bp, off);
            if (ov > bv || (ov == bv && op < bp)) { bv = ov; bp = op; }
        }
        if (lane == 0) { red_v[w] = bv; red_p[w] = bp; }
        __syncthreads();
        if (t == 0) {
            float Bv = red_v[0]; int Bp = red_p[0];
            for (int q = 1; q < 4; ++q)
                if (red_v[q] > Bv || (red_v[q] == Bv && red_p[q] < Bp)) {
                    Bv = red_v[q]; Bp = red_p[q];
                }
            topi[it] = ci[Bp];
            sv[Bp] = -FLT_MAX;
        }
        __syncthreads();
    }

    const float4* sp = (const float4*)(src + (size_t)row * DIM);
    #pragma unroll
    for (int q = 0; q < 4; ++q) {
        int cidx = topi[w + 4 * q];
        const float4* tp = (const float4*)(tgt + (size_t)cidx * DIM);
        float a = 0.f, nn = 0.f;
        #pragma unroll
        for (int p = 0; p < 4; ++p) {
            float4 x = sp[lane + 64 * p], y = tp[lane + 64 * p];
            a  = fmaf(x.x, y.x, a);  a  = fmaf(x.y, y.y, a);
            a  = fmaf(x.z, y.z, a);  a  = fmaf(x.w, y.w, a);
            nn = fmaf(y.x, y.x, nn); nn = fmaf(y.y, y.y, nn);
            nn = fmaf(y.z, y.z, nn); nn = fmaf(y.w, y.w, nn);
        }
        #pragma unroll
        for (int off = 1; off < 64; off <<= 1) {
            a  += __shfl_xor(a, off);
            nn += __shfl_xor(nn, off);
        }
        if (lane == 0) { rsim[w + 4 * q] = a / sqrtf(nn); ridx[w + 4 * q] = cidx; }
    }
    __syncthreads();

    if (w == 0) {
        float v = (lane < RERANK) ? rsim[lane] : -FLT_MAX;
        int  ix = (lane < RERANK) ? ridx[lane] : 0x7fffffff;
        #pragma unroll
        for (int it = 0; it < KNN; ++it) {
            float bv = v; int bix = ix;
            #pragma unroll
            for (int off = 1; off < 16; off <<= 1) {
                float ov = __shfl_xor(bv, off);
                int   oi = __shfl_xor(bix, off);
                if (ov > bv || (ov == bv && oi < bix)) { bv = ov; bix = oi; }
            }
            if (lane == 0) sel[it] = bix;
            if (ix == bix) v = -FLT_MAX;
        }
    }
    __syncthreads();

    const float4* g0 = (const float4*)(tgt + (size_t)sel[0] * DIM);
    const float4* g1 = (const float4*)(tgt + (size_t)sel[1] * DIM);
    const float4* g2 = (const float4*)(tgt + (size_t)sel[2] * DIM);
    const float4* g3 = (const float4*)(tgt + (size_t)sel[3] * DIM);
    float4* po = (float4*)(out + (size_t)row * DIM);
    float4 v0 = g0[t], v1 = g1[t], v2 = g2[t], v3 = g3[t];
    float4 rr;
    rr.x = (v0.x + v1.x + v2.x + v3.x) * 0.25f;
    rr.y = (v0.y + v1.y + v2.y + v3.y) * 0.25f;
    rr.z = (v0.z + v1.z + v2.z + v3.z) * 0.25f;
    rr.w = (v0.w + v1.w + v2.w + v3.w) * 0.25f;
    po[t] = rr;
}

// ---------------------------------------------------------------------------
extern "C" void kernel_launch(void* const* d_in, const int* in_sizes, int n_in,
                              void* d_out, int out_size, void* d_ws, size_t ws_size,
                              hipStream_t stream)
{
    const float* src = (const float*)d_in[0];
    const float* tgt = (const float*)d_in[1];
    float* out = (float*)d_out;

    const size_t SRCBF_B = 2097152;                       // 2 MB
    const size_t TGTBF_B = (size_t)N_TGT2 * 2048;         // 204,996,608
    const size_t INVN_B  = (size_t)N_TGT2 * 4;            // 400,384
    const size_t CV_B    = (size_t)N_SRC * NCAND * 4;     // 12,812,288
    const size_t NEED    = SRCBF_B + TGTBF_B + INVN_B + 2 * CV_B;

    char* p = (char*)d_ws;

    if (ws_size >= NEED) {
        // big-ws path: prep both operands to bf16, pure-gload GEMM
        unsigned int* srcbf = (unsigned int*)p;
        unsigned int* tgtbf = (unsigned int*)(p + SRCBF_B);
        float* invnw    = (float*)(p + SRCBF_B + TGTBF_B);
        float* cand_val = (float*)(p + SRCBF_B + TGTBF_B + INVN_B);
        int*   cand_idx = (int*)(p + SRCBF_B + TGTBF_B + INVN_B + CV_B);

        convert_src_kernel<<<512, 256, 0, stream>>>(src, srcbf);
        prep_tgt_kernel<<<N_TGT2 / 16, 256, 0, stream>>>(tgt, tgtbf, invnw);
        gemm_topk_bf_kernel<<<NBLK, 512, 0, stream>>>(tgtbf, srcbf, invnw,
                                                      cand_val, cand_idx);
        merge_rerank_kernel<<<N_SRC, 256, 0, stream>>>(src, tgt,
                                                       cand_val, cand_idx, out);
    } else {
        // fallback: round-5 path (f32 A staged in-loop)
        unsigned int* srcbf = (unsigned int*)p;
        float* cand_val = (float*)(p + SRCBF_B);
        int*   cand_idx = (int*)(p + SRCBF_B + CV_B);

        convert_src_kernel<<<512, 256, 0, stream>>>(src, srcbf);
        gemm_topk_old_kernel<<<NBLK, 512, 0, stream>>>(tgt, srcbf,
                                                       cand_val, cand_idx);
        merge_rerank_kernel<<<N_SRC, 256, 0, stream>>>(src, tgt,
                                                       cand_val, cand_idx, out);
    }
}